// Round 8
// baseline (421.231 us; speedup 1.0000x reference)
//
#include <hip/hip_runtime.h>
#include <hip/hip_bf16.h>
#include <stdint.h>

#define N_NODES   100000
#define N_EDGES   3200000
#define IN_FEAT   128
#define OUT_FEAT  128
#define NUM_RELS  16
#define NUM_BASES 8
#define M_PAD     100096      // 782 * 128
#define NBKT      391         // coarse buckets = ceil(100000/256)
#define NB        512         // blocks in coarse hist/place (must match both)

using short8 = __attribute__((ext_vector_type(8))) short;
using v4f    = __attribute__((ext_vector_type(4))) float;
using f32x2  = __attribute__((ext_vector_type(2))) float;

__device__ inline unsigned short f2bf_rne(float f) {
    __hip_bfloat16 h = __float2bfloat16(f);
    return *reinterpret_cast<unsigned short*>(&h);
}
__device__ inline float asf(uint32_t u) {
    union { uint32_t i; float f; } x; x.i = u; return x.f;
}

// ---------------------------------------------------------------------------
// x fp32 -> bf16, zero-padded to M_PAD rows
// ---------------------------------------------------------------------------
__global__ void conv_x(const float* __restrict__ x, unsigned short* __restrict__ xb) {
    int id = blockIdx.x * 256 + threadIdx.x;
    int base = id * 4;
    ushort4 o;
    if (base < N_NODES * IN_FEAT) {
        const float4 v = reinterpret_cast<const float4*>(x)[id];
        o.x = f2bf_rne(v.x); o.y = f2bf_rne(v.y);
        o.z = f2bf_rne(v.z); o.w = f2bf_rne(v.w);
    } else {
        o.x = o.y = o.z = o.w = 0;
    }
    reinterpret_cast<ushort4*>(xb)[id] = o;
}

// ---------------------------------------------------------------------------
// Ut[o][b*128+i] = bf16(weight[b][i][o]) -- basis matrices, transposed so
// both zgemm operands are row-major-over-K. 128 x 1024 bf16 = 256 KB.
// ---------------------------------------------------------------------------
__global__ void build_ut(const float* __restrict__ weight,
                         unsigned short* __restrict__ Ut) {
    int id = blockIdx.x * 256 + threadIdx.x;   // 512 blocks * 256 = 131072
    int o  = id >> 10;
    int kk = id & 1023;
    int b  = kk >> 7;
    int i  = kk & 127;
    Ut[id] = f2bf_rne(weight[(b * IN_FEAT + i) * OUT_FEAT + o]);
}

// ---------------------------------------------------------------------------
// Sort by dst. Coarse bucket b = dst>>8.
// Phase 1: per-block LDS histogram -> histG[b*NB + nb]  (no global atomics)
// ---------------------------------------------------------------------------
__global__ __launch_bounds__(512) void coarse_hist(const int* __restrict__ dst,
                                                   int* __restrict__ histG,
                                                   int nbuck) {
    extern __shared__ int lh[];
    for (int i = threadIdx.x; i < nbuck; i += 512) lh[i] = 0;
    __syncthreads();
    const int NG = N_EDGES / 4;
    const int stride = NB * 512;
    for (int g = blockIdx.x * 512 + threadIdx.x; g < NG; g += stride) {
        const int4 d4 = reinterpret_cast<const int4*>(dst)[g];
        atomicAdd(&lh[d4.x >> 8], 1);
        atomicAdd(&lh[d4.y >> 8], 1);
        atomicAdd(&lh[d4.z >> 8], 1);
        atomicAdd(&lh[d4.w >> 8], 1);
    }
    __syncthreads();
    for (int i = threadIdx.x; i < nbuck; i += 512)
        histG[i * NB + blockIdx.x] = lh[i];
}

// ---------------------------------------------------------------------------
// 2-level in-place exclusive scan of data[0..K): part -> mid -> final
// ---------------------------------------------------------------------------
__global__ void scan_part(const int* __restrict__ data, int* __restrict__ partial, int K) {
    __shared__ int sh[256];
    const int tid = threadIdx.x, b = blockIdx.x;
    const int i0 = b * 4096 + tid * 16;
    int s = 0;
#pragma unroll
    for (int k = 0; k < 16; ++k) { int i = i0 + k; if (i < K) s += data[i]; }
    sh[tid] = s;
    __syncthreads();
    for (int st = 128; st > 0; st >>= 1) {
        if (tid < st) sh[tid] += sh[tid + st];
        __syncthreads();
    }
    if (tid == 0) partial[b] = sh[0];
}

__global__ __launch_bounds__(512) void scan_mid(int* __restrict__ partial, int G) {
    __shared__ int sh[512];
    const int tid = threadIdx.x;
    int v = (tid < G) ? partial[tid] : 0;
    sh[tid] = v;
    __syncthreads();
    for (int st = 1; st < 512; st <<= 1) {
        int t = (tid >= st) ? sh[tid - st] : 0;
        __syncthreads();
        sh[tid] += t;
        __syncthreads();
    }
    if (tid < G) partial[tid] = sh[tid] - v;        // exclusive
}

// in-place: each element read before overwrite by the same thread
__global__ void scan_final(int* __restrict__ data, const int* __restrict__ partial, int K) {
    __shared__ int sh[256];
    const int tid = threadIdx.x, b = blockIdx.x;
    const int i0 = b * 4096 + tid * 16;
    int s = 0;
#pragma unroll
    for (int k = 0; k < 16; ++k) { int i = i0 + k; if (i < K) s += data[i]; }
    sh[tid] = s;
    __syncthreads();
    for (int st = 1; st < 256; st <<= 1) {
        int t = (tid >= st) ? sh[tid - st] : 0;
        __syncthreads();
        sh[tid] += t;
        __syncthreads();
    }
    int run = partial[b] + sh[tid] - s;
#pragma unroll
    for (int k = 0; k < 16; ++k) {
        int i = i0 + k;
        if (i < K) {
            int c = data[i];
            data[i] = run;
            run += c;
        }
    }
}

// ---------------------------------------------------------------------------
// Phase 2: place edges into bucket-contiguous regions using exact reserved
// ranges (histS = scanned histG). LDS cursors only.
// entry = (dst&255)<<21 | rl<<17 | src   (29 bits; src < 2^17)
// ---------------------------------------------------------------------------
__global__ __launch_bounds__(512) void coarse_place(const int* __restrict__ src,
                                                    const int* __restrict__ dst,
                                                    const int* __restrict__ et,
                                                    const int* __restrict__ histS,
                                                    int* __restrict__ entries,
                                                    int nbuck) {
    extern __shared__ int cur[];
    for (int i = threadIdx.x; i < nbuck; i += 512)
        cur[i] = histS[i * NB + blockIdx.x];
    __syncthreads();
    const int NG = N_EDGES / 4;
    const int stride = NB * 512;
    for (int g = blockIdx.x * 512 + threadIdx.x; g < NG; g += stride) {
        const int4 s4 = reinterpret_cast<const int4*>(src)[g];
        const int4 d4 = reinterpret_cast<const int4*>(dst)[g];
        const int4 t4 = reinterpret_cast<const int4*>(et)[g];
        int p0 = atomicAdd(&cur[d4.x >> 8], 1);
        int p1 = atomicAdd(&cur[d4.y >> 8], 1);
        int p2 = atomicAdd(&cur[d4.z >> 8], 1);
        int p3 = atomicAdd(&cur[d4.w >> 8], 1);
        entries[p0] = ((d4.x & 255) << 21) | ((t4.x & 15) << 17) | s4.x;
        entries[p1] = ((d4.y & 255) << 21) | ((t4.y & 15) << 17) | s4.y;
        entries[p2] = ((d4.z & 255) << 21) | ((t4.z & 15) << 17) | s4.z;
        entries[p3] = ((d4.w & 255) << 21) | ((t4.w & 15) << 17) | s4.w;
    }
}

// ---------------------------------------------------------------------------
// Phase 3: one block per bucket; counting sort by 12-bit key (dlow<<4 | rl)
// in LDS (2-pass). Edge lists become rel-contiguous per node, enabling the
// run-flush gather. Thread tid owns exactly dlow==tid (16 consecutive keys).
// perm entry = rl<<17 | src (21 bits).
// ---------------------------------------------------------------------------
__global__ __launch_bounds__(256) void fine_sort(const int* __restrict__ entries,
                                                 const int* __restrict__ histS,
                                                 int* __restrict__ perm,
                                                 int* __restrict__ off,
                                                 int nbuck) {
    __shared__ int cnt[4096];
    __shared__ int bs[256];
    const int tid = threadIdx.x, b = blockIdx.x;
    const int start = histS[b * NB];
    const int end   = (b + 1 < nbuck) ? histS[(b + 1) * NB] : N_EDGES;

#pragma unroll
    for (int k = 0; k < 16; ++k) cnt[tid * 16 + k] = 0;
    __syncthreads();
    for (int i = start + tid; i < end; i += 256)
        atomicAdd(&cnt[entries[i] >> 17], 1);
    __syncthreads();

    int c[16];
    int tsum = 0;
#pragma unroll
    for (int k = 0; k < 16; ++k) { c[k] = cnt[tid * 16 + k]; tsum += c[k]; }
    bs[tid] = tsum;
    __syncthreads();
    for (int st = 1; st < 256; st <<= 1) {
        int t = (tid >= st) ? bs[tid - st] : 0;
        __syncthreads();
        bs[tid] += t;
        __syncthreads();
    }
    const int excl = bs[tid] - tsum;   // exclusive prefix of this dlow group

    const int d = b * 256 + tid;
    if (d < N_NODES) off[d] = start + excl;
    if (b == nbuck - 1 && tid == 0) off[N_NODES] = N_EDGES;

    int run = excl;
#pragma unroll
    for (int k = 0; k < 16; ++k) { cnt[tid * 16 + k] = run; run += c[k]; }
    __syncthreads();
    for (int i = start + tid; i < end; i += 256) {
        int en = entries[i];
        int p = atomicAdd(&cnt[en >> 17], 1);
        perm[start + p] = en & 0x1FFFFF;   // rl<<17 | src
    }
}

// ---------------------------------------------------------------------------
// Basis-space aggregation with rel-run grouping, PACKED-f32 math: all inner
// arithmetic on f32x2 ext-vectors so the compiler emits v_pk_add_f32 /
// v_pk_fma_f32 (2 FLOPs/slot). w_comp is staged in LDS as duplicated (c,c)
// pairs so the flush is 8 pk-FMAs from 4 ds_read_b128.
// zb stores are plain (NOT non-temporal): round-7 showed nt does not protect
// xb in L3 (FETCH 360 -> 342 MB, noise) and only forces zgemm to re-read zb
// from HBM. Plain stores leave zb MALL-hot for the immediately-following
// zgemm.
// ---------------------------------------------------------------------------
__global__ void gather_z(const int* __restrict__ off, const int* __restrict__ perm,
                         const unsigned short* __restrict__ xb,
                         const float* __restrict__ w_comp,
                         unsigned short* __restrict__ zb) {
    __shared__ f32x2 csh[NUM_RELS * NUM_BASES];   // duplicated pairs, 1 KB
    if (threadIdx.x < NUM_RELS * NUM_BASES) {
        float c = w_comp[threadIdx.x];
        csh[threadIdx.x] = (f32x2){c, c};
    }
    __syncthreads();
    const int d = blockIdx.x * 4 + (threadIdx.x >> 6);
    const int lane = threadIdx.x & 63;
    f32x2 z[8];
#pragma unroll
    for (int b = 0; b < 8; ++b) z[b] = (f32x2){0.f, 0.f};

    if (d < N_NODES) {
        const int e0 = off[d], e1 = off[d + 1];
        const uint32_t* xl = reinterpret_cast<const uint32_t*>(xb) + lane;
        int cur = -1;
        f32x2 srun = (f32x2){0.f, 0.f};

        auto flush = [&]() {
            const f32x2* cp = &csh[cur * 8];
#pragma unroll
            for (int b = 0; b < 8; ++b)
                z[b] += cp[b] * srun;              // v_pk_fma_f32
        };
        auto step = [&](int p, uint32_t u) {
            int rl = p >> 17;
            if (rl != cur) {                       // wave-uniform branch
                flush();
                cur = rl;
                srun = (f32x2){0.f, 0.f};
            }
            f32x2 xv;
            xv.x = asf(u << 16);
            xv.y = asf(u & 0xFFFF0000u);
            srun += xv;                            // v_pk_add_f32
        };

        if (e0 < e1) {
            cur = perm[e0] >> 17;                  // first run: no leading flush
            int e = e0;
            for (; e + 8 <= e1; e += 8) {
                int p[8];
#pragma unroll
                for (int j = 0; j < 8; ++j) p[j] = perm[e + j];
                uint32_t v[8];
#pragma unroll
                for (int j = 0; j < 8; ++j)
                    v[j] = xl[(size_t)(p[j] & 0x1FFFF) * 64];
#pragma unroll
                for (int j = 0; j < 8; ++j) step(p[j], v[j]);
            }
            for (; e < e1; ++e) {
                int p = perm[e];
                uint32_t v = xl[(size_t)(p & 0x1FFFF) * 64];
                step(p, v);
            }
            flush();                               // final run
        }
    }

    // store z row (pad rows d in [N_NODES, M_PAD) get zeros so zgemm reads clean)
    unsigned short* zr = zb + (size_t)d * 1024 + lane * 2;
#pragma unroll
    for (int b = 0; b < 8; ++b) {
        unsigned int u = (unsigned int)f2bf_rne(z[b].x)
                       | ((unsigned int)f2bf_rne(z[b].y) << 16);
        *reinterpret_cast<unsigned int*>(zr + b * 128) = u;
    }
}

// ---------------------------------------------------------------------------
// out = z (M_PAD x 1024) * Ut^T (128 x 1024) + bias.  m97-style 128x128 tile
// with 8-step K-loop via global_load_lds(16B), XOR-swizzled LDS.
// ---------------------------------------------------------------------------
__global__ __launch_bounds__(256, 2) void zgemm(const unsigned short* __restrict__ zb,
                                                const unsigned short* __restrict__ Ut,
                                                const float* __restrict__ bias,
                                                float* __restrict__ out) {
    __shared__ unsigned short lA[128 * 128];
    __shared__ unsigned short lB[128 * 128];

    const int mb = blockIdx.x;
    const int tid  = threadIdx.x;
    const int wid  = tid >> 6;
    const int lane = tid & 63;
    const int wm = wid >> 1, wn = wid & 1;
    const int ml = lane & 15, kgrp = lane >> 4;

    const unsigned short* gA = zb + (size_t)mb * 128 * 1024;

    v4f acc[4][4];
#pragma unroll
    for (int i = 0; i < 4; ++i)
#pragma unroll
        for (int j = 0; j < 4; ++j)
            acc[i][j] = (v4f){0.f, 0.f, 0.f, 0.f};

    for (int kt = 0; kt < 8; ++kt) {
#pragma unroll
        for (int it = 0; it < 8; ++it) {
            int sbase = it * 256 + wid * 64;
            int s = sbase + lane;
            int row = s >> 4;
            int cc = (s & 15) ^ (row & 15);
            __builtin_amdgcn_global_load_lds(
                (const __attribute__((address_space(1))) void*)(gA + (size_t)row * 1024 + kt * 128 + cc * 8),
                (__attribute__((address_space(3))) void*)(&lA[sbase * 8]), 16, 0, 0);
            __builtin_amdgcn_global_load_lds(
                (const __attribute__((address_space(1))) void*)(Ut + (size_t)row * 1024 + kt * 128 + cc * 8),
                (__attribute__((address_space(3))) void*)(&lB[sbase * 8]), 16, 0, 0);
        }
        __syncthreads();

#pragma unroll
        for (int kb = 0; kb < 4; ++kb) {
            const int cc = kb * 4 + kgrp;
            short8 af[4], bfr[4];
#pragma unroll
            for (int tm = 0; tm < 4; ++tm) {
                int rA = wm * 64 + tm * 16 + ml;
                af[tm] = *reinterpret_cast<const short8*>(&lA[(rA * 16 + (cc ^ (rA & 15))) * 8]);
            }
#pragma unroll
            for (int tn = 0; tn < 4; ++tn) {
                int rB = wn * 64 + tn * 16 + ml;
                bfr[tn] = *reinterpret_cast<const short8*>(&lB[(rB * 16 + (cc ^ (rB & 15))) * 8]);
            }
#pragma unroll
            for (int tm = 0; tm < 4; ++tm)
#pragma unroll
                for (int tn = 0; tn < 4; ++tn)
                    acc[tm][tn] = __builtin_amdgcn_mfma_f32_16x16x32_bf16(af[tm], bfr[tn], acc[tm][tn], 0, 0, 0);
        }
        __syncthreads();
    }

    const int row0 = mb * 128 + wm * 64;
    const int col0 = wn * 64;
#pragma unroll
    for (int tm = 0; tm < 4; ++tm)
#pragma unroll
        for (int rr = 0; rr < 4; ++rr) {
            int row = row0 + tm * 16 + kgrp * 4 + rr;
            if (row < N_NODES) {
                size_t rb = (size_t)row * OUT_FEAT;
#pragma unroll
                for (int tn = 0; tn < 4; ++tn) {
                    int col = col0 + tn * 16 + ml;
                    out[rb + col] = acc[tm][tn][rr] + bias[col];
                }
            }
        }
}

static inline size_t align256(size_t a) { return (a + 255) & ~(size_t)255; }

extern "C" void kernel_launch(void* const* d_in, const int* in_sizes, int n_in,
                              void* d_out, int out_size, void* d_ws, size_t ws_size,
                              hipStream_t stream) {
    const float* x      = (const float*)d_in[0];
    const float* weight = (const float*)d_in[1];
    const float* w_comp = (const float*)d_in[2];
    const float* h_bias = (const float*)d_in[3];
    const int*   src    = (const int*)d_in[4];
    const int*   dst    = (const int*)d_in[5];
    const int*   etypes = (const int*)d_in[6];
    float* out = (float*)d_out;

    const int nbuck = NBKT;
    const int K2 = nbuck * NB;                 // 200192
    const int G2 = (K2 + 4095) / 4096;         // 49

    // Workspace layout (total ~244 MB):
    //   Ut 512KB | xb 25.6MB | perm 12.8MB | off 0.4MB | partial | zb 205MB
    // entries (12.8MB) and histG (0.8MB) alias zb -- dead before gather_z.
    size_t a = 512 * 1024;                                    // Ut
    size_t xb_o = a;   a = align256(a + (size_t)M_PAD * 128 * 2);
    size_t perm_o = a; a = align256(a + (size_t)N_EDGES * 4);
    size_t off_o = a;  a = align256(a + ((size_t)N_NODES + 1) * 4);
    size_t part_o = a; a = align256(a + 512 * 4);
    size_t zb_o = a;   // zb: M_PAD * 1024 * 2 = 205 MB

    char* w = (char*)d_ws;
    unsigned short* Ut      = (unsigned short*)(w);
    unsigned short* xb      = (unsigned short*)(w + xb_o);
    int*            perm    = (int*)(w + perm_o);
    int*            off     = (int*)(w + off_o);
    int*            partial = (int*)(w + part_o);
    unsigned short* zb      = (unsigned short*)(w + zb_o);
    int*            entries = (int*)(w + zb_o);                    // alias zb
    int*            histG   = (int*)(w + zb_o + 13 * 1024 * 1024); // alias zb+13MB

    conv_x<<<12512, 256, 0, stream>>>(x, xb);
    build_ut<<<512, 256, 0, stream>>>(weight, Ut);

    coarse_hist<<<NB, 512, nbuck * 4, stream>>>(dst, histG, nbuck);
    scan_part<<<G2, 256, 0, stream>>>(histG, partial, K2);
    scan_mid<<<1, 512, 0, stream>>>(partial, G2);
    scan_final<<<G2, 256, 0, stream>>>(histG, partial, K2);
    coarse_place<<<NB, 512, nbuck * 4, stream>>>(src, dst, etypes, histG, entries, nbuck);
    fine_sort<<<nbuck, 256, 0, stream>>>(entries, histG, perm, off, nbuck);

    gather_z<<<25024, 256, 0, stream>>>(off, perm, xb, w_comp, zb);
    zgemm<<<782, 256, 0, stream>>>(zb, Ut, h_bias, out);
}